// Round 8
// baseline (692.365 us; speedup 1.0000x reference)
//
#include <hip/hip_runtime.h>
#include <stdint.h>

#define NSUP   50000
#define NSUPP  50176      // padded to multiple of 128 (and 256)
#define NQRY   2048
#define KD     512
#define BK     32
#define NKT    16         // KD / BK

typedef __attribute__((ext_vector_type(8))) short bf16x8;
typedef __attribute__((ext_vector_type(4))) float f32x4;

__device__ __forceinline__ unsigned short f2bf(float f) {
  unsigned int u = __float_as_uint(f);
  u += 0x7FFFu + ((u >> 16) & 1u);   // round-to-nearest-even
  return (unsigned short)(u >> 16);
}

// ---- prep: fused norm + normalize + f32->bf16 (+ zero pad rows) ----
__global__ __launch_bounds__(256) void prep_kernel(
    const float* __restrict__ sup, const float* __restrict__ qry,
    unsigned short* __restrict__ s_bf, unsigned short* __restrict__ q_bf) {
  const int row  = blockIdx.x * 4 + (threadIdx.x >> 6);
  const int lane = threadIdx.x & 63;

  const float* src = nullptr;
  unsigned short* dst;
  if (row < NSUPP) {
    dst = s_bf + (size_t)row * KD;
    if (row < NSUP) src = sup + (size_t)row * KD;
  } else {
    const int r = row - NSUPP;
    dst = q_bf + (size_t)r * KD;
    src = qry + (size_t)r * KD;
  }

  if (src == nullptr) {           // zero pad row
    bf16x8 z = {};
    *(bf16x8*)(dst + lane * 8) = z;
    return;
  }

  const float4 v0 = ((const float4*)src)[lane * 2 + 0];
  const float4 v1 = ((const float4*)src)[lane * 2 + 1];
  float ss = v0.x*v0.x + v0.y*v0.y + v0.z*v0.z + v0.w*v0.w
           + v1.x*v1.x + v1.y*v1.y + v1.z*v1.z + v1.w*v1.w;
  #pragma unroll
  for (int off = 32; off > 0; off >>= 1) ss += __shfl_xor(ss, off);
  const float inv = rsqrtf(fmaxf(ss, 1e-30f));

  bf16x8 o;
  o[0]=(short)f2bf(v0.x*inv); o[1]=(short)f2bf(v0.y*inv);
  o[2]=(short)f2bf(v0.z*inv); o[3]=(short)f2bf(v0.w*inv);
  o[4]=(short)f2bf(v1.x*inv); o[5]=(short)f2bf(v1.y*inv);
  o[6]=(short)f2bf(v1.z*inv); o[7]=(short)f2bf(v1.w*inv);
  *(bf16x8*)(dst + lane * 8) = o;
}

// ---- stage one 8KB K-tile unit (128 rows x 32 cols bf16), 4 waves ----
// Linear LDS dest; bank-swizzle via permuted GLOBAL source chunk (rule 21):
// LDS granule [row][c] holds global chunk c ^ ((row>>1)&3).
__device__ __forceinline__ void stage_unit(const unsigned short* __restrict__ g,
                                           unsigned short* lds, int grow_base,
                                           int kt, int w, int l) {
  const int chunk = (l & 3) ^ ((l >> 3) & 3);   // ((row>>1)&3) == (l>>3)&3 here
  #pragma unroll
  for (int i = 0; i < 2; ++i) {
    const unsigned short* src = g + (size_t)(grow_base + i*64 + w*16 + (l>>2)) * KD
                                  + kt*BK + chunk*8;
    unsigned short* dst = lds + i*2048 + w*512;  // wave-uniform base (+lane*16B)
    __builtin_amdgcn_global_load_lds(
        (const __attribute__((address_space(1))) void*)src,
        (__attribute__((address_space(3))) void*)dst, 16, 0, 0);
  }
}

// swizzled fragment-read element offset for row R, k-granule hi (0..3)
#define SWZ_OFF(R, hi) (((hi) ^ (((R) >> 1) & 3)) * 8)

// ---- GEMM: out[q][s] = dot(q_bf[q], s_bf[s])  (inputs pre-normalized) ----
// INSTRUMENTED ROUND: identical R6 structure, but the whole computation is
// repeated REP=2 times inside the kernel (re-zero acc, re-stage, re-store
// identical bytes -> idempotent & deterministic). Purpose: push the GEMM
// dispatch to ~410us so it tops the rocprof top-5 and we finally see its
// MfmaUtil / VALUBusy / Occupancy / LDS_CONFLICT / FETCH / WRITE.
__global__ __launch_bounds__(256, 3) void gemm_kernel(
    const unsigned short* __restrict__ S,   // [NSUPP][KD] normalized bf16
    const unsigned short* __restrict__ Q,   // [NQRY][KD]  normalized bf16
    float* __restrict__ out) {              // [NQRY][NSUP]
  __shared__ __attribute__((aligned(16))) unsigned short As[2][128][BK];
  __shared__ __attribute__((aligned(16))) unsigned short Bs[2][128][BK];

  const int tid = threadIdx.x;
  const int w = tid >> 6, l = tid & 63;
  const int wr = w >> 1, wc = w & 1;       // wave -> 64x64 quadrant
  const int rof = l & 15, hi = l >> 4;

  // XCD swizzle: 6272 blocks, 6272 % 8 == 0 -> bijective.
  int bid = blockIdx.y * 392 + blockIdx.x;
  bid = (bid & 7) * 784 + (bid >> 3);
  const int ts = (bid % 392) * 128;        // support tile base (padded domain)
  const int tq = (bid / 392) * 128;        // query tile base

  #pragma unroll 1
  for (int rep = 0; rep < 2; ++rep) {
    f32x4 acc[4][4] = {};

    // prologue: stage K-tile 0 into slot 0
    stage_unit(S, &As[0][0][0], ts, 0, w, l);
    stage_unit(Q, &Bs[0][0][0], tq, 0, w, l);
    __syncthreads();

    #pragma unroll
    for (int t = 0; t < NKT; ++t) {
      const int slot = t & 1;
      if (t + 1 < NKT) {                   // prefetch next K-tile into other slot
        stage_unit(S, &As[slot ^ 1][0][0], ts, t + 1, w, l);
        stage_unit(Q, &Bs[slot ^ 1][0][0], tq, t + 1, w, l);
      }

      bf16x8 a[4], b[4];
      #pragma unroll
      for (int i = 0; i < 4; ++i) {
        const int R = wr*64 + i*16 + rof;
        a[i] = *(const bf16x8*)&As[slot][R][SWZ_OFF(R, hi)];
      }
      #pragma unroll
      for (int i = 0; i < 4; ++i) {
        const int R = wc*64 + i*16 + rof;
        b[i] = *(const bf16x8*)&Bs[slot][R][SWZ_OFF(R, hi)];
      }

      #pragma unroll
      for (int mi = 0; mi < 4; ++mi)
        #pragma unroll
        for (int ni = 0; ni < 4; ++ni)
          acc[mi][ni] = __builtin_amdgcn_mfma_f32_16x16x32_bf16(a[mi], b[ni], acc[mi][ni], 0, 0, 0);

      __syncthreads();
    }

    // ---- epilogue: D row = support (contiguous 4) -> dwordx4 stores ----
    #pragma unroll
    for (int mi = 0; mi < 4; ++mi) {
      const int s = ts + wr*64 + mi*16 + hi*4;  // 4 consecutive supports
      if (s < NSUP) {                            // s%4==0, NSUP%4==0 -> all-or-none
        #pragma unroll
        for (int ni = 0; ni < 4; ++ni) {
          const int q = tq + wc*64 + ni*16 + rof;
          *(f32x4*)(out + (size_t)q * NSUP + s) = acc[mi][ni];   // dwordx4
        }
      }
    }
    __syncthreads();   // rep isolation: epilogue reads done before re-staging
  }
}

extern "C" void kernel_launch(void* const* d_in, const int* in_sizes, int n_in,
                              void* d_out, int out_size, void* d_ws, size_t ws_size,
                              hipStream_t stream) {
  const float* sup = (const float*)d_in[0];   // [50000][512] f32
  const float* qry = (const float*)d_in[1];   // [2048][512] f32
  float* out = (float*)d_out;                 // [2048][50000] f32

  char* ws = (char*)d_ws;
  unsigned short* s_bf = (unsigned short*)(ws);
  unsigned short* q_bf = (unsigned short*)(ws + (size_t)NSUPP * KD * 2);
  // ws use: 50176*512*2 + 2048*512*2 = 53.5 MB

  prep_kernel<<<(NSUPP + NQRY) / 4, 256, 0, stream>>>(sup, qry, s_bf, q_bf);

  dim3 grid(392, 16);   // support tiles x query tiles -> 6272 blocks
  gemm_kernel<<<grid, 256, 0, stream>>>(s_bf, q_bf, out);
}

// Round 11
// 251.391 us; speedup vs baseline: 2.7541x; 2.7541x over previous
//
#include <hip/hip_runtime.h>
#include <stdint.h>

#define NSUP   50000
#define NSUPP  50176      // padded to multiple of 128 (and 256)
#define NQRY   2048
#define KD     512
#define BK     32
#define NKT    16         // KD / BK

typedef __attribute__((ext_vector_type(8))) short bf16x8;
typedef __attribute__((ext_vector_type(4))) float f32x4;

__device__ __forceinline__ unsigned short f2bf(float f) {
  unsigned int u = __float_as_uint(f);
  u += 0x7FFFu + ((u >> 16) & 1u);   // round-to-nearest-even
  return (unsigned short)(u >> 16);
}

// ---- prep: fused norm + normalize + f32->bf16 (+ zero pad rows) ----
__global__ __launch_bounds__(256) void prep_kernel(
    const float* __restrict__ sup, const float* __restrict__ qry,
    unsigned short* __restrict__ s_bf, unsigned short* __restrict__ q_bf) {
  const int row  = blockIdx.x * 4 + (threadIdx.x >> 6);
  const int lane = threadIdx.x & 63;

  const float* src = nullptr;
  unsigned short* dst;
  if (row < NSUPP) {
    dst = s_bf + (size_t)row * KD;
    if (row < NSUP) src = sup + (size_t)row * KD;
  } else {
    const int r = row - NSUPP;
    dst = q_bf + (size_t)r * KD;
    src = qry + (size_t)r * KD;
  }

  if (src == nullptr) {           // zero pad row
    bf16x8 z = {};
    *(bf16x8*)(dst + lane * 8) = z;
    return;
  }

  const float4 v0 = ((const float4*)src)[lane * 2 + 0];
  const float4 v1 = ((const float4*)src)[lane * 2 + 1];
  float ss = v0.x*v0.x + v0.y*v0.y + v0.z*v0.z + v0.w*v0.w
           + v1.x*v1.x + v1.y*v1.y + v1.z*v1.z + v1.w*v1.w;
  #pragma unroll
  for (int off = 32; off > 0; off >>= 1) ss += __shfl_xor(ss, off);
  const float inv = rsqrtf(fmaxf(ss, 1e-30f));

  bf16x8 o;
  o[0]=(short)f2bf(v0.x*inv); o[1]=(short)f2bf(v0.y*inv);
  o[2]=(short)f2bf(v0.z*inv); o[3]=(short)f2bf(v0.w*inv);
  o[4]=(short)f2bf(v1.x*inv); o[5]=(short)f2bf(v1.y*inv);
  o[6]=(short)f2bf(v1.z*inv); o[7]=(short)f2bf(v1.w*inv);
  *(bf16x8*)(dst + lane * 8) = o;
}

// ---- stage one 8KB K-tile unit (128 rows x 32 cols bf16), 4 waves ----
// Linear LDS dest; bank-swizzle via permuted GLOBAL source chunk (rule 21):
// LDS granule [row][c] holds global chunk c ^ ((row>>1)&3).
__device__ __forceinline__ void stage_unit(const unsigned short* __restrict__ g,
                                           unsigned short* lds, int grow_base,
                                           int kt, int w, int l) {
  const int chunk = (l & 3) ^ ((l >> 3) & 3);   // ((row>>1)&3) == (l>>3)&3 here
  #pragma unroll
  for (int i = 0; i < 2; ++i) {
    const unsigned short* src = g + (size_t)(grow_base + i*64 + w*16 + (l>>2)) * KD
                                  + kt*BK + chunk*8;
    unsigned short* dst = lds + i*2048 + w*512;  // wave-uniform base (+lane*16B)
    __builtin_amdgcn_global_load_lds(
        (const __attribute__((address_space(1))) void*)src,
        (__attribute__((address_space(3))) void*)dst, 16, 0, 0);
  }
}

// swizzled fragment-read element offset for row R, k-granule hi (0..3)
#define SWZ_OFF(R, hi) (((hi) ^ (((R) >> 1) & 3)) * 8)

// ---- GEMM: out[q][s] = dot(q_bf[q], s_bf[s])  (inputs pre-normalized) ----
// 128x128 tile, 4 waves (2x2), BK=32, double-buffered LDS (32 KB), 3 blocks/CU.
// Support-major XCD ownership. Each XCD owns 49 support tiles x all 16
// query tiles, query-fastest: the 2 MB query set stays L2-resident and each
// 131 KB support tile is fetched past L2 ONCE (16 temporally-adjacent blocks
// share it) -> predicted FETCH ~70 MB vs 680 MB with the old q-major swizzle.
__global__ __launch_bounds__(256, 3) void gemm_kernel(
    const unsigned short* __restrict__ S,   // [NSUPP][KD] normalized bf16
    const unsigned short* __restrict__ Q,   // [NQRY][KD]  normalized bf16
    float* __restrict__ out) {              // [NQRY][NSUP]
  __shared__ __attribute__((aligned(16))) unsigned short As[2][128][BK];
  __shared__ __attribute__((aligned(16))) unsigned short Bs[2][128][BK];

  const int tid = threadIdx.x;
  const int w = tid >> 6, l = tid & 63;
  const int wr = w >> 1, wc = w & 1;       // wave -> 64x64 quadrant
  const int rof = l & 15, hi = l >> 4;

  // support-major XCD decode: 6272 blocks = 8 XCDs x 49 stiles x 16 qtiles
  const int orig  = blockIdx.x;
  const int xcd   = orig & 7;
  const int idx   = orig >> 3;             // dispatch order within XCD
  const int stile = xcd * 49 + (idx >> 4); // support tile (slow)
  const int qtile = idx & 15;              // query tile (fast)
  const int ts = stile * 128;
  const int tq = qtile * 128;

  f32x4 acc[4][4] = {};

  // prologue: stage K-tile 0 into slot 0
  stage_unit(S, &As[0][0][0], ts, 0, w, l);
  stage_unit(Q, &Bs[0][0][0], tq, 0, w, l);
  __syncthreads();

  #pragma unroll
  for (int t = 0; t < NKT; ++t) {
    const int slot = t & 1;
    if (t + 1 < NKT) {                     // prefetch next K-tile into other slot
      stage_unit(S, &As[slot ^ 1][0][0], ts, t + 1, w, l);
      stage_unit(Q, &Bs[slot ^ 1][0][0], tq, t + 1, w, l);
    }

    bf16x8 a[4], b[4];
    #pragma unroll
    for (int i = 0; i < 4; ++i) {
      const int R = wr*64 + i*16 + rof;
      a[i] = *(const bf16x8*)&As[slot][R][SWZ_OFF(R, hi)];
    }
    #pragma unroll
    for (int i = 0; i < 4; ++i) {
      const int R = wc*64 + i*16 + rof;
      b[i] = *(const bf16x8*)&Bs[slot][R][SWZ_OFF(R, hi)];
    }

    #pragma unroll
    for (int mi = 0; mi < 4; ++mi)
      #pragma unroll
      for (int ni = 0; ni < 4; ++ni)
        acc[mi][ni] = __builtin_amdgcn_mfma_f32_16x16x32_bf16(a[mi], b[ni], acc[mi][ni], 0, 0, 0);

    __syncthreads();
  }

  // ---- epilogue: D row = support (contiguous 4) -> dwordx4 stores ----
  #pragma unroll
  for (int mi = 0; mi < 4; ++mi) {
    const int s = ts + wr*64 + mi*16 + hi*4;    // 4 consecutive supports
    if (s < NSUP) {                              // s%4==0, NSUP%4==0 -> all-or-none
      #pragma unroll
      for (int ni = 0; ni < 4; ++ni) {
        const int q = tq + wc*64 + ni*16 + rof;
        *(f32x4*)(out + (size_t)q * NSUP + s) = acc[mi][ni];   // dwordx4
      }
    }
  }
}

extern "C" void kernel_launch(void* const* d_in, const int* in_sizes, int n_in,
                              void* d_out, int out_size, void* d_ws, size_t ws_size,
                              hipStream_t stream) {
  const float* sup = (const float*)d_in[0];   // [50000][512] f32
  const float* qry = (const float*)d_in[1];   // [2048][512] f32
  float* out = (float*)d_out;                 // [2048][50000] f32

  char* ws = (char*)d_ws;
  unsigned short* s_bf = (unsigned short*)(ws);
  unsigned short* q_bf = (unsigned short*)(ws + (size_t)NSUPP * KD * 2);
  // ws use: 50176*512*2 + 2048*512*2 = 53.5 MB

  prep_kernel<<<(NSUPP + NQRY) / 4, 256, 0, stream>>>(sup, qry, s_bf, q_bf);

  gemm_kernel<<<6272, 256, 0, stream>>>(s_bf, q_bf, out);
}

// Round 12
// 201.868 us; speedup vs baseline: 3.4298x; 1.2453x over previous
//
#include <hip/hip_runtime.h>
#include <stdint.h>

#define NSUP   50000
#define NSUPP  50176      // padded to multiple of 128 (and 256)
#define NQRY   2048
#define KD     512
#define BK     32
#define NKT    16         // KD / BK

typedef __attribute__((ext_vector_type(8))) short bf16x8;
typedef __attribute__((ext_vector_type(4))) float f32x4;

__device__ __forceinline__ unsigned short f2bf(float f) {
  unsigned int u = __float_as_uint(f);
  u += 0x7FFFu + ((u >> 16) & 1u);   // round-to-nearest-even
  return (unsigned short)(u >> 16);
}

// ---- prep: fused norm + normalize + f32->bf16 (+ zero pad rows) ----
__global__ __launch_bounds__(256) void prep_kernel(
    const float* __restrict__ sup, const float* __restrict__ qry,
    unsigned short* __restrict__ s_bf, unsigned short* __restrict__ q_bf) {
  const int row  = blockIdx.x * 4 + (threadIdx.x >> 6);
  const int lane = threadIdx.x & 63;

  const float* src = nullptr;
  unsigned short* dst;
  if (row < NSUPP) {
    dst = s_bf + (size_t)row * KD;
    if (row < NSUP) src = sup + (size_t)row * KD;
  } else {
    const int r = row - NSUPP;
    dst = q_bf + (size_t)r * KD;
    src = qry + (size_t)r * KD;
  }

  if (src == nullptr) {           // zero pad row
    bf16x8 z = {};
    *(bf16x8*)(dst + lane * 8) = z;
    return;
  }

  const float4 v0 = ((const float4*)src)[lane * 2 + 0];
  const float4 v1 = ((const float4*)src)[lane * 2 + 1];
  float ss = v0.x*v0.x + v0.y*v0.y + v0.z*v0.z + v0.w*v0.w
           + v1.x*v1.x + v1.y*v1.y + v1.z*v1.z + v1.w*v1.w;
  #pragma unroll
  for (int off = 32; off > 0; off >>= 1) ss += __shfl_xor(ss, off);
  const float inv = rsqrtf(fmaxf(ss, 1e-30f));

  bf16x8 o;
  o[0]=(short)f2bf(v0.x*inv); o[1]=(short)f2bf(v0.y*inv);
  o[2]=(short)f2bf(v0.z*inv); o[3]=(short)f2bf(v0.w*inv);
  o[4]=(short)f2bf(v1.x*inv); o[5]=(short)f2bf(v1.y*inv);
  o[6]=(short)f2bf(v1.z*inv); o[7]=(short)f2bf(v1.w*inv);
  *(bf16x8*)(dst + lane * 8) = o;
}

// ---- stage one 8KB K-tile unit (128 rows x 32 cols bf16), 4 waves ----
// Linear LDS dest; bank-swizzle via permuted GLOBAL source chunk (rule 21):
// LDS granule [row][c] holds global chunk c ^ ((row>>1)&3).
__device__ __forceinline__ void stage_unit(const unsigned short* __restrict__ g,
                                           unsigned short* lds, int grow_base,
                                           int kt, int w, int l) {
  const int chunk = (l & 3) ^ ((l >> 3) & 3);   // ((row>>1)&3) == (l>>3)&3 here
  #pragma unroll
  for (int i = 0; i < 2; ++i) {
    const unsigned short* src = g + (size_t)(grow_base + i*64 + w*16 + (l>>2)) * KD
                                  + kt*BK + chunk*8;
    unsigned short* dst = lds + i*2048 + w*512;  // wave-uniform base (+lane*16B)
    __builtin_amdgcn_global_load_lds(
        (const __attribute__((address_space(1))) void*)src,
        (__attribute__((address_space(3))) void*)dst, 16, 0, 0);
  }
}

// swizzled fragment-read element offset for row R, k-granule hi (0..3)
#define SWZ_OFF(R, hi) (((hi) ^ (((R) >> 1) & 3)) * 8)

// ---- GEMM: out[q][s] = dot(q_bf[q], s_bf[s])  (inputs pre-normalized) ----
// 128x128 tile, 4 waves (2x2), BK=32, double-buffered LDS (32 KB), 3 blocks/CU,
// support-major XCD ownership (49 stiles x 16 qtiles per XCD, query-fastest).
// NEW this round: NON-TEMPORAL output stores. Theory: the 410 MB output
// stream write-allocates ~6 MB of lines per XCD's 4 MB L2, evicting operand
// tiles -> zero reuse (FETCH 680 MB, R8) regardless of block mapping (R11
// null). nt stores bypass L2 allocation -> operands stay resident, support-
// major reuse engages, write amplification (670->410 MB) drops.
__global__ __launch_bounds__(256, 3) void gemm_kernel(
    const unsigned short* __restrict__ S,   // [NSUPP][KD] normalized bf16
    const unsigned short* __restrict__ Q,   // [NQRY][KD]  normalized bf16
    float* __restrict__ out) {              // [NQRY][NSUP]
  __shared__ __attribute__((aligned(16))) unsigned short As[2][128][BK];
  __shared__ __attribute__((aligned(16))) unsigned short Bs[2][128][BK];

  const int tid = threadIdx.x;
  const int w = tid >> 6, l = tid & 63;
  const int wr = w >> 1, wc = w & 1;       // wave -> 64x64 quadrant
  const int rof = l & 15, hi = l >> 4;

  // support-major XCD decode: 6272 blocks = 8 XCDs x 49 stiles x 16 qtiles
  const int orig  = blockIdx.x;
  const int xcd   = orig & 7;
  const int idx   = orig >> 3;             // dispatch order within XCD
  const int stile = xcd * 49 + (idx >> 4); // support tile (slow)
  const int qtile = idx & 15;              // query tile (fast)
  const int ts = stile * 128;
  const int tq = qtile * 128;

  f32x4 acc[4][4] = {};

  // prologue: stage K-tile 0 into slot 0
  stage_unit(S, &As[0][0][0], ts, 0, w, l);
  stage_unit(Q, &Bs[0][0][0], tq, 0, w, l);
  __syncthreads();

  #pragma unroll
  for (int t = 0; t < NKT; ++t) {
    const int slot = t & 1;
    if (t + 1 < NKT) {                     // prefetch next K-tile into other slot
      stage_unit(S, &As[slot ^ 1][0][0], ts, t + 1, w, l);
      stage_unit(Q, &Bs[slot ^ 1][0][0], tq, t + 1, w, l);
    }

    bf16x8 a[4], b[4];
    #pragma unroll
    for (int i = 0; i < 4; ++i) {
      const int R = wr*64 + i*16 + rof;
      a[i] = *(const bf16x8*)&As[slot][R][SWZ_OFF(R, hi)];
    }
    #pragma unroll
    for (int i = 0; i < 4; ++i) {
      const int R = wc*64 + i*16 + rof;
      b[i] = *(const bf16x8*)&Bs[slot][R][SWZ_OFF(R, hi)];
    }

    #pragma unroll
    for (int mi = 0; mi < 4; ++mi)
      #pragma unroll
      for (int ni = 0; ni < 4; ++ni)
        acc[mi][ni] = __builtin_amdgcn_mfma_f32_16x16x32_bf16(a[mi], b[ni], acc[mi][ni], 0, 0, 0);

    __syncthreads();
  }

  // ---- epilogue: non-temporal dwordx4 stores (output never re-read) ----
  #pragma unroll
  for (int mi = 0; mi < 4; ++mi) {
    const int s = ts + wr*64 + mi*16 + hi*4;    // 4 consecutive supports
    if (s < NSUP) {                              // s%4==0, NSUP%4==0 -> all-or-none
      #pragma unroll
      for (int ni = 0; ni < 4; ++ni) {
        const int q = tq + wc*64 + ni*16 + rof;
        __builtin_nontemporal_store(acc[mi][ni],
                                    (f32x4*)(out + (size_t)q * NSUP + s));
      }
    }
  }
}

extern "C" void kernel_launch(void* const* d_in, const int* in_sizes, int n_in,
                              void* d_out, int out_size, void* d_ws, size_t ws_size,
                              hipStream_t stream) {
  const float* sup = (const float*)d_in[0];   // [50000][512] f32
  const float* qry = (const float*)d_in[1];   // [2048][512] f32
  float* out = (float*)d_out;                 // [2048][50000] f32

  char* ws = (char*)d_ws;
  unsigned short* s_bf = (unsigned short*)(ws);
  unsigned short* q_bf = (unsigned short*)(ws + (size_t)NSUPP * KD * 2);
  // ws use: 50176*512*2 + 2048*512*2 = 53.5 MB

  prep_kernel<<<(NSUPP + NQRY) / 4, 256, 0, stream>>>(sup, qry, s_bf, q_bf);

  gemm_kernel<<<6272, 256, 0, stream>>>(s_bf, q_bf, out);
}